// Round 1
// baseline (1411.550 us; speedup 1.0000x reference)
//
#include <hip/hip_runtime.h>
#include <hip/hip_bf16.h>

#define SEQ 8
#define H 512
#define EPS 1e-5f
#define NROWS 65536
#define NOUT 256

typedef __hip_bfloat16 bf16;
typedef __attribute__((ext_vector_type(8))) short bf16x8;   // 8 bf16 = 4 VGPRs
typedef __attribute__((ext_vector_type(4))) float f32x4;

#define GLOAD_LDS16(g, l)                                               \
    __builtin_amdgcn_global_load_lds(                                   \
        (const __attribute__((address_space(1))) unsigned int*)(g),     \
        (__attribute__((address_space(3))) unsigned int*)(l), 16, 0, 0)

// ---------------------------------------------------------------------------
// K0: convert + transpose out_W fp32 [512][256] -> Wt bf16 [256][512]
// (k-contiguous per n, so K2 can stage B with global_load_lds width-16).
// ---------------------------------------------------------------------------
__global__ __launch_bounds__(64) void k0_convW(const float* __restrict__ W,
                                               bf16* __restrict__ Wt)
{
    const int u = blockIdx.x * 64 + threadIdx.x;   // 0..16383
    const int n = u >> 6;                          // 0..255
    const int k0 = (u & 63) * 8;                   // 0..504
    bf16 tmp[8];
#pragma unroll
    for (int i = 0; i < 8; ++i)
        tmp[i] = __float2bfloat16(W[(long)(k0 + i) * NOUT + n]);
    *(ushort4*)(Wt + (long)n * H + k0)     = *(ushort4*)&tmp[0];
    *(ushort4*)(Wt + (long)n * H + k0 + 4) = *(ushort4*)&tmp[4];
}

// ---------------------------------------------------------------------------
// K1: wave-per-row LayerNorm + neighbor attention softmax + pool.
// ONE-PASS STREAMING (online softmax accumulation): x tiles are consumed
// immediately, never held resident -> ~70 VGPRs instead of ~150, so 2x the
// waves/SIMD and enough loads in flight to stream x at HBM rate.
//
// Math (per row):
//   logit'_s   = r_s * (sum_i wg_i x_si - m_s * sum_i wg_i),  wg = gamma*wn
//     (node term, attn_b, and sum_i beta_i*wn_i are constant over s: cancel)
//   att_s      = e_s / den,   e_s = exp(logit'_s)   (no max-sub: |logit|~O(1))
//   pooled_i   = (sum_s e_s r_s x_si - sum_s e_s r_s m_s) / den
//   fused_i    = gamma_i*(xhat0_i + pooled_i) + 2*beta_i     (sum att = 1)
// ---------------------------------------------------------------------------
__global__ __launch_bounds__(256) void k1_ln_attn_pool(
    const float* __restrict__ x,
    const float* __restrict__ gamma,
    const float* __restrict__ beta,
    const float* __restrict__ attn_W,
    bf16* __restrict__ fused)
{
    const int lane = threadIdx.x & 63;
    const int wave = threadIdx.x >> 6;
    const long row = (long)blockIdx.x * 4 + wave;
    const int h0 = lane << 2;                      // elems h0..h0+3, h0+256..+259
    const float* xr = x + row * (long)(SEQ * H);

    // ---- weights: gg = gamma, wg = gamma * wn (logit weights) ----
    float gg[8], wg[8];
    {
        float4 a = *(const float4*)(gamma + h0);
        float4 b = *(const float4*)(gamma + 256 + h0);
        gg[0]=a.x; gg[1]=a.y; gg[2]=a.z; gg[3]=a.w;
        gg[4]=b.x; gg[5]=b.y; gg[6]=b.z; gg[7]=b.w;
        a = *(const float4*)(attn_W + H + h0);
        b = *(const float4*)(attn_W + H + 256 + h0);
        wg[0]=gg[0]*a.x; wg[1]=gg[1]*a.y; wg[2]=gg[2]*a.z; wg[3]=gg[3]*a.w;
        wg[4]=gg[4]*b.x; wg[5]=gg[5]*b.y; wg[6]=gg[6]*b.z; wg[7]=gg[7]*b.w;
    }

    // ---- issue node-row + first-neighbor loads early ----
    float4 c0a = *(const float4*)(xr + h0);
    float4 c0b = *(const float4*)(xr + 256 + h0);
    float4 na  = *(const float4*)(xr + H + h0);
    float4 nb  = *(const float4*)(xr + H + 256 + h0);

    // wgs = sum_i wg_i over all 512 (wave reduce; overlaps the loads above)
    float wgs = ((wg[0]+wg[1])+(wg[2]+wg[3]))+((wg[4]+wg[5])+(wg[6]+wg[7]));
#pragma unroll
    for (int off = 32; off > 0; off >>= 1) wgs += __shfl_xor(wgs, off, 64);

    // ---- s = 0 (node): stats only; keep raw x0 for the epilogue ----
    float x0[8];
    x0[0]=c0a.x; x0[1]=c0a.y; x0[2]=c0a.z; x0[3]=c0a.w;
    x0[4]=c0b.x; x0[5]=c0b.y; x0[6]=c0b.z; x0[7]=c0b.w;
    float s0 = 0.0f, q0 = 0.0f;
#pragma unroll
    for (int i = 0; i < 8; ++i) { s0 += x0[i]; q0 = fmaf(x0[i], x0[i], q0); }
#pragma unroll
    for (int off = 32; off > 0; off >>= 1) {
        s0 += __shfl_xor(s0, off, 64);
        q0 += __shfl_xor(q0, off, 64);
    }
    const float m0 = s0 * (1.0f / H);
    const float r0 = rsqrtf(fmaf(-m0, m0, q0 * (1.0f / H)) + EPS);

    // ---- neighbors s = 1..7: streaming online accumulation ----
    float p[8] = {0,0,0,0,0,0,0,0};
    float den = 0.0f, corr = 0.0f;
#pragma unroll
    for (int s = 1; s < SEQ; ++s) {
        float xc[8];
        xc[0]=na.x; xc[1]=na.y; xc[2]=na.z; xc[3]=na.w;
        xc[4]=nb.x; xc[5]=nb.y; xc[6]=nb.z; xc[7]=nb.w;
        if (s < SEQ - 1) {   // prefetch next tile while we reduce this one
            na = *(const float4*)(xr + (s + 1) * H + h0);
            nb = *(const float4*)(xr + (s + 1) * H + 256 + h0);
        }
        float su = 0.0f, sq = 0.0f, dw = 0.0f;
#pragma unroll
        for (int i = 0; i < 8; ++i) {
            su += xc[i];
            sq  = fmaf(xc[i], xc[i], sq);
            dw  = fmaf(wg[i], xc[i], dw);
        }
#pragma unroll
        for (int off = 32; off > 0; off >>= 1) {   // 3 independent chains
            su += __shfl_xor(su, off, 64);
            sq += __shfl_xor(sq, off, 64);
            dw += __shfl_xor(dw, off, 64);
        }
        const float m  = su * (1.0f / H);
        const float r  = rsqrtf(fmaf(-m, m, sq * (1.0f / H)) + EPS);
        const float lg = r * fmaf(-m, wgs, dw);
        const float e  = __expf(lg);               // safe: |lg| = O(1) << 88
        den += e;
        const float er = e * r;
        corr = fmaf(er, m, corr);
#pragma unroll
        for (int i = 0; i < 8; ++i) p[i] = fmaf(er, xc[i], p[i]);
    }

    // ---- epilogue ----
    const float rd  = 1.0f / den;
    const float nm0 = -m0 * r0;
    float b2[8];
    {
        float4 a = *(const float4*)(beta + h0);
        float4 b = *(const float4*)(beta + 256 + h0);
        b2[0]=2.f*a.x; b2[1]=2.f*a.y; b2[2]=2.f*a.z; b2[3]=2.f*a.w;
        b2[4]=2.f*b.x; b2[5]=2.f*b.y; b2[6]=2.f*b.z; b2[7]=2.f*b.w;
    }
    union { ushort4 u[2]; bf16 h[8]; } ow;
#pragma unroll
    for (int i = 0; i < 8; ++i) {
        float t = fmaf(r0, x0[i], nm0);            // xhat0
        t += (p[i] - corr) * rd;                   // + pooled
        ow.h[i] = __float2bfloat16(fmaf(gg[i], t, b2[i]));
    }
    *(ushort4*)(fused + row * H + h0)       = ow.u[0];
    *(ushort4*)(fused + row * H + 256 + h0) = ow.u[1];
}

// ---------------------------------------------------------------------------
// K2: out = relu(fused @ out_W + out_b) via bf16 MFMA.
// fused bf16 [65536][512], Wt bf16 [256][512] (pre-transposed), out fp32.
// Block = 256 thr (4 waves) -> 128x128 tile; wave = 64x64 (4x4 of 16x16x32).
// Bijective XCD swizzle (2048 % 8 == 0) keeps the two n-halves of an A-tile
// on the same XCD so A is fetched once per XCD L2.
// ---------------------------------------------------------------------------
__global__ __launch_bounds__(256) void k2_mfma_gemm(
    const bf16* __restrict__ A,
    const bf16* __restrict__ Wt,
    const float* __restrict__ bias,
    float* __restrict__ out)
{
    __shared__ bf16 Asl[4096];   // 4 kb * 128 m * 8 j = 8 KiB
    __shared__ bf16 Bsl[4096];   // 4 kb * 128 n * 8 j = 8 KiB

    const int tid  = threadIdx.x;
    const int w    = tid >> 6;
    const int lane = tid & 63;

    const int nwg = gridDim.x;                       // 2048
    int bid = blockIdx.x;
    bid = (bid & 7) * (nwg >> 3) + (bid >> 3);       // XCD-aware, bijective

    const long row0 = (long)(bid >> 1) * 128;
    const int  n0   = (bid & 1) * 128;

    const int wm = w & 1;        // wave m-half (0/1)
    const int wn = w >> 1;       // wave n-half (0/1)
    const int q   = lane >> 4;   // k-octet quad
    const int r16 = lane & 15;

    f32x4 acc[4][4];
#pragma unroll
    for (int i = 0; i < 4; ++i)
#pragma unroll
        for (int j = 0; j < 4; ++j) acc[i][j] = (f32x4){0.f, 0.f, 0.f, 0.f};

    const bf16* ag = A  + (row0 + lane) * (long)H + w * 8;
    const bf16* bg = Wt + (n0   + lane) * (long)H + w * 8;

    for (int kc = 0; kc < H; kc += 32) {
        GLOAD_LDS16(ag + kc,           Asl + w * 1024);        // rows 0..63
        GLOAD_LDS16(ag + kc + 64 * H,  Asl + w * 1024 + 512);  // rows 64..127
        GLOAD_LDS16(bg + kc,           Bsl + w * 1024);        // cols 0..63
        GLOAD_LDS16(bg + kc + 64 * H,  Bsl + w * 1024 + 512);  // cols 64..127
        __syncthreads();

        bf16x8 afr[4], bfr[4];
#pragma unroll
        for (int t = 0; t < 4; ++t) {
            afr[t] = *(const bf16x8*)(Asl + q * 1024 + (wm * 64 + t * 16 + r16) * 8);
            bfr[t] = *(const bf16x8*)(Bsl + q * 1024 + (wn * 64 + t * 16 + r16) * 8);
        }
#pragma unroll
        for (int tm = 0; tm < 4; ++tm)
#pragma unroll
            for (int tn = 0; tn < 4; ++tn)
                acc[tm][tn] = __builtin_amdgcn_mfma_f32_16x16x32_bf16(
                    afr[tm], bfr[tn], acc[tm][tn], 0, 0, 0);
        __syncthreads();
    }

    // Epilogue: C/D layout col = lane&15, row = q*4 + reg.
#pragma unroll
    for (int tn = 0; tn < 4; ++tn) {
        const int col = n0 + wn * 64 + tn * 16 + r16;
        const float bv = bias[col];
#pragma unroll
        for (int tm = 0; tm < 4; ++tm) {
            const long rbase = row0 + wm * 64 + tm * 16 + q * 4;
#pragma unroll
            for (int r = 0; r < 4; ++r)
                out[(rbase + r) * NOUT + col] = fmaxf(acc[tm][tn][r] + bv, 0.0f);
        }
    }
}

extern "C" void kernel_launch(void* const* d_in, const int* in_sizes, int n_in,
                              void* d_out, int out_size, void* d_ws, size_t ws_size,
                              hipStream_t stream) {
    const float* x      = (const float*)d_in[0];
    const float* gamma  = (const float*)d_in[1];
    const float* beta   = (const float*)d_in[2];
    const float* attn_W = (const float*)d_in[3];
    // d_in[4] = attn_b: cancels in softmax
    const float* out_W  = (const float*)d_in[5];
    const float* out_b  = (const float*)d_in[6];
    float* out = (float*)d_out;

    bf16* fused = (bf16*)d_ws;                                  // 64 MiB
    bf16* Wt    = (bf16*)((char*)d_ws + (size_t)64 * 1024 * 1024);  // 256 KiB

    k0_convW<<<256, 64, 0, stream>>>(out_W, Wt);
    k1_ln_attn_pool<<<NROWS / 4, 256, 0, stream>>>(x, gamma, beta, attn_W, fused);
    k2_mfma_gemm<<<(NROWS / 128) * 2, 256, 0, stream>>>(fused, Wt, out_b, out);
}